// Round 15
// baseline (21.135 us; speedup 1.0000x reference)
//
#include <hip/hip_runtime.h>
#include <math.h>

#define BB 2
#define NN 4096
#define CC 33
#define RP 40                         // bf16 row pitch in ushorts (80 B): probs 0..32,
                                      // pad 33, sqn f32 in 34..35, pad 36..39
#define TILE 64
#define NTILES (NN / TILE)            // 64
#define NJT 5                         // j-tiles per block
#define NPB 442                       // sum over ti of ceil((64-ti)/5)
#define ROWBLK 256                    // 256 blocks x 32 rows (8 rows/wave, 8 lanes/row)
#define PAIRBLK (BB * NPB)            // 884 pair blocks
#define NSLOT 64
#define SLOTSTR 32                    // 128 B between slots (distinct L2 lines)

typedef __attribute__((ext_vector_type(8))) short frag_ab;   // 8 bf16 (4 VGPRs)
typedef __attribute__((ext_vector_type(4))) float f32x4;     // 4 fp32 accum

__device__ __forceinline__ float fast_sqrt(float x) {
    return __builtin_amdgcn_sqrtf(x);                        // v_sqrt_f32, ~2 ULP
}
__device__ __forceinline__ unsigned f2bf(float x) {          // RNE, x >= 0 finite
    unsigned u = __float_as_uint(x);
    return (u + 0x7FFFu + ((u >> 16) & 1u)) >> 16;
}
__device__ __forceinline__ float bf2f(unsigned b) {
    return __uint_as_float(b << 16);
}

// ---------------- kernel 1: softmax, 8 rows/wave (8 lanes x 4 classes each;
// class 32 on group leader). sqn packed into row pad (ushorts 34..35).
__global__ __launch_bounds__(256) void row_kernel(
    const float* __restrict__ pred, const int* __restrict__ targets,
    const int* __restrict__ pred_choice, unsigned short* __restrict__ p16,
    float2* __restrict__ part_row, int* __restrict__ part_match,
    float* __restrict__ slotf, unsigned* __restrict__ subcnt,
    unsigned* __restrict__ master)
{
    __shared__ __align__(16) float sraw[32 * CC];     // 4.2 KB
    __shared__ float2 lds_cf[4];
    __shared__ int lds_mt[4];

    if (blockIdx.x == 0) {
        for (int i = threadIdx.x; i < NSLOT * SLOTSTR; i += 256) {
            slotf[i] = 0.0f;
            subcnt[i] = 0u;
        }
        if (threadIdx.x == 0) *master = 0u;
    }

    {   // flat coalesced staging: 32 rows = 1056 floats = 264 float4 (aligned)
        const float4* src = (const float4*)(pred + (size_t)blockIdx.x * 32 * CC);
        float4* dst = (float4*)sraw;
        for (int k = threadIdx.x; k < 264; k += 256) dst[k] = src[k];
    }
    __syncthreads();

    int l = threadIdx.x & 63;
    int w = threadIdx.x >> 6;
    int r = l >> 3;                    // row within wave (0..7)
    int c = l & 7;                     // class chunk: classes 4c..4c+3
    int rloc = w * 8 + r;              // row within block (0..31)
    int row = blockIdx.x * 32 + rloc;

    float v[4];
    #pragma unroll
    for (int k = 0; k < 4; k++) v[k] = sraw[rloc * CC + 4 * c + k];
    float v32 = sraw[rloc * CC + 32];

    float m = fmaxf(fmaxf(v[0], v[1]), fmaxf(v[2], v[3]));
    if (c == 0) m = fmaxf(m, v32);
    m = fmaxf(m, __shfl_xor(m, 1));
    m = fmaxf(m, __shfl_xor(m, 2));
    m = fmaxf(m, __shfl_xor(m, 4));

    float e[4];
    float s = 0.0f;
    #pragma unroll
    for (int k = 0; k < 4; k++) { e[k] = __expf(v[k] - m); s += e[k]; }
    float e32 = __expf(v32 - m);
    if (c == 0) s += e32;
    s += __shfl_xor(s, 1);
    s += __shfl_xor(s, 2);
    s += __shfl_xor(s, 4);
    float inv = 1.0f / s;

    // pack rounded bf16 probs + sqn in ROUNDED space
    unsigned pb[4];
    float sq = 0.0f;
    #pragma unroll
    for (int k = 0; k < 4; k++) {
        pb[k] = f2bf(e[k] * inv);
        float pf = bf2f(pb[k]);
        sq += pf * pf;
    }
    unsigned c32u = f2bf(e32 * inv);
    float c32 = bf2f(c32u);
    if (c == 0) sq += c32 * c32;
    sq += __shfl_xor(sq, 1);
    sq += __shfl_xor(sq, 2);
    sq += __shfl_xor(sq, 4);

    {   // 8B packed store: classes 4c..4c+3
        uint2 st = make_uint2(pb[0] | (pb[1] << 16), pb[2] | (pb[3] << 16));
        *(uint2*)&p16[(size_t)row * RP + 4 * c] = st;
    }
    if (c == 0) {                      // ushorts 32..39: c32, 0, sq(f32), 0, 0
        uint4 st = make_uint4(c32u, __float_as_uint(sq), 0u, 0u);
        *(uint4*)&p16[(size_t)row * RP + 32] = st;
    }

    // CE / focal / match (raw-space prob of target class)
    int tg = targets[row];
    float cand = 0.0f;
    if (tg < 32) {
        int cc = tg >> 2, kk = tg & 3;
        if (cc == c) cand = e[kk];
    } else if (c == 0) cand = e32;
    cand += __shfl_xor(cand, 1);
    cand += __shfl_xor(cand, 2);
    cand += __shfl_xor(cand, 4);

    float ce = 0.0f, fo = 0.0f; int mt = 0;
    if (c == 0) {
        float pt = cand * inv;
        ce = -__logf(pt);
        float om = 1.0f - pt;
        fo = om * om;
        mt = (tg == pred_choice[row]) ? 1 : 0;
    }
    ce += __shfl_xor(ce, 8);  ce += __shfl_xor(ce, 16);  ce += __shfl_xor(ce, 32);
    fo += __shfl_xor(fo, 8);  fo += __shfl_xor(fo, 16);  fo += __shfl_xor(fo, 32);
    mt += __shfl_xor(mt, 8);  mt += __shfl_xor(mt, 16);  mt += __shfl_xor(mt, 32);

    if (l == 0) { lds_cf[w] = make_float2(ce, fo); lds_mt[w] = mt; }
    __syncthreads();
    if (threadIdx.x == 0) {
        float2 a = lds_cf[0], b2 = lds_cf[1], c2 = lds_cf[2], d = lds_cf[3];
        part_row[blockIdx.x] = make_float2(a.x + b2.x + c2.x + d.x,
                                           a.y + b2.y + c2.y + d.y);
        part_match[blockIdx.x] = lds_mt[0] + lds_mt[1] + lds_mt[2] + lds_mt[3];
    }
}

// ---------------- kernel 2: 64x320 Gram tiles via bf16 MFMA. One i-tile x
// up to 5 j-tiles per block (A-frag reused x20 MFMAs). sqn from the row pad.
// Fence-free 64-slot completion protocol (uneven counts 13/14); winner block
// finalizes.
__global__ __launch_bounds__(256) void pair_kernel(
    const unsigned short* __restrict__ p16,
    const float2* __restrict__ part_row, const int* __restrict__ part_match,
    float* __restrict__ slotf, unsigned* __restrict__ subcnt,
    unsigned* __restrict__ master, float* __restrict__ out)
{
    __shared__ __align__(16) unsigned short spi[TILE * RP];
    __shared__ __align__(16) unsigned short spj[NJT * TILE * RP];
    __shared__ float red[4];
    __shared__ int lastFlag;
    __shared__ double lds_ce[4], lds_fo[4], lds_pr[4];
    __shared__ int lds_mt[4];

    int bid = blockIdx.x;
    int b = bid / NPB;
    int t = bid % NPB;

    // decode: row ti has ceil((64-ti)/NJT) blocks (block-uniform scalar loop)
    int ti = 0, rem = t;
    while (rem >= (NTILES - ti + NJT - 1) / NJT) {
        rem -= (NTILES - ti + NJT - 1) / NJT; ++ti;
    }
    int tjA = ti + NJT * rem;
    int avail = NTILES - tjA; if (avail > NJT) avail = NJT;
    bool diagA = (tjA == ti);
    int i0 = ti * TILE, j0A = tjA * TILE;

    // linear staging: i-tile + avail j-tiles, all contiguous 5120B chunks
    {
        const float4* srci = (const float4*)(p16 + ((size_t)b * NN + i0) * RP);
        const float4* srcj = (const float4*)(p16 + ((size_t)b * NN + j0A) * RP);
        float4* di = (float4*)spi;
        float4* dj = (float4*)spj;
        int jf4 = avail * 320;
        for (int k = threadIdx.x; k < 320; k += 256) di[k] = srci[k];
        for (int k = threadIdx.x; k < jf4; k += 256) dj[k] = srcj[k];
    }
    __syncthreads();

    int l = threadIdx.x & 63;
    int w = threadIdx.x >> 6;          // wave = 16-row strip of the i-tile
    int col = l & 15;
    int kc = l >> 4;                   // k-chunk 0..3 (8 bf16 each)

    // A fragment: rows 16w..16w+15 of i-tile, k = kc*8..kc*8+7 (reused x20)
    frag_ab afr = *(const frag_ab*)&spi[(16 * w + col) * RP + kc * 8];

    // per-lane row metadata from the row pad (C layout rows 16w+kc*4+r)
    float qi[4], c32a[4];
    #pragma unroll
    for (int r = 0; r < 4; r++) {
        int ir = 16 * w + kc * 4 + r;
        qi[r]   = __uint_as_float(*(const unsigned*)&spi[ir * RP + 34]);
        c32a[r] = bf2f(spi[ir * RP + 32]);
    }
    int gi0 = i0 + 16 * w + kc * 4;    // gi = gi0 + r

    float ssum = 0.0f;

    #pragma unroll
    for (int jt = 0; jt < NJT; jt++) {
        if (jt >= avail) break;                      // block-uniform
        const unsigned short* spjx = spj + jt * TILE * RP;
        int j0 = j0A + jt * TILE;
        bool dg = (jt == 0) && diagA;

        #pragma unroll
        for (int n = 0; n < 4; n++) {  // 16-col subtiles of this j-tile
            int jr = 16 * n + col;
            frag_ab bfr = *(const frag_ab*)&spjx[jr * RP + kc * 8];
            f32x4 acc = {0.0f, 0.0f, 0.0f, 0.0f};
            acc = __builtin_amdgcn_mfma_f32_16x16x32_bf16(afr, bfr, acc, 0, 0, 0);

            float c32b = bf2f(spjx[jr * RP + 32]);
            float qj   = __uint_as_float(*(const unsigned*)&spjx[jr * RP + 34]);
            int   gj   = j0 + 16 * n + col;

            #pragma unroll
            for (int r = 0; r < 4; r++) {
                float g  = fmaf(c32a[r], c32b, acc[r]);      // + class-32 term
                float d2 = fmaf(-2.0f, g, qi[r] + qj);
                float d  = fast_sqrt(fmaxf(d2, 0.0f));
                ssum += (!dg || gj > gi0 + r) ? d : 0.0f;    // strict upper on diag
            }
        }
    }

    #pragma unroll
    for (int off = 32; off; off >>= 1) ssum += __shfl_xor(ssum, off);
    if (l == 0) red[w] = ssum;
    __syncthreads();

    if (threadIdx.x == 0) {
        float blockSum = red[0] + red[1] + red[2] + red[3];
        int slotIdx = bid & (NSLOT - 1);
        int slot = slotIdx * SLOTSTR;
        unsigned expect = (unsigned)(PAIRBLK / NSLOT) + (slotIdx < (PAIRBLK % NSLOT) ? 1u : 0u);
        __hip_atomic_fetch_add(&slotf[slot], blockSum,
                               __ATOMIC_RELAXED, __HIP_MEMORY_SCOPE_AGENT);
        asm volatile("s_waitcnt vmcnt(0)" ::: "memory");   // order fadd before count
        unsigned o = __hip_atomic_fetch_add(&subcnt[slot], 1u,
                                            __ATOMIC_RELAXED, __HIP_MEMORY_SCOPE_AGENT);
        int last = 0;
        if (o == expect - 1) {                             // last block of this slot
            unsigned o2 = __hip_atomic_fetch_add(master, 1u,
                                                 __ATOMIC_RELAXED, __HIP_MEMORY_SCOPE_AGENT);
            last = (o2 == NSLOT - 1);
        }
        lastFlag = last;
    }
    __syncthreads();
    if (!lastFlag) return;

    // ---- fused finalize (winner block only; slots coherent via agent atomics,
    //      part_* via kernel-boundary) ----
    double ce = 0.0, fo = 0.0, pr = 0.0;
    int mt = 0;
    for (int i = threadIdx.x; i < ROWBLK; i += 256) {
        float2 v = part_row[i];
        ce += (double)v.x;
        fo += (double)v.y;
        mt += part_match[i];
    }
    for (int i = threadIdx.x; i < NSLOT; i += 256)
        pr += (double)__hip_atomic_load(&slotf[i * SLOTSTR],
                                        __ATOMIC_RELAXED, __HIP_MEMORY_SCOPE_AGENT);

    #pragma unroll
    for (int off = 32; off; off >>= 1) {
        ce += __shfl_xor(ce, off);
        fo += __shfl_xor(fo, off);
        pr += __shfl_xor(pr, off);
        mt += __shfl_xor(mt, off);
    }
    if (l == 0) { lds_ce[w] = ce; lds_fo[w] = fo; lds_pr[w] = pr; lds_mt[w] = mt; }
    __syncthreads();
    if (threadIdx.x == 0) {
        double tce = lds_ce[0] + lds_ce[1] + lds_ce[2] + lds_ce[3];
        double tfo = lds_fo[0] + lds_fo[1] + lds_fo[2] + lds_fo[3];
        double tpr = lds_pr[0] + lds_pr[1] + lds_pr[2] + lds_pr[3];
        int    tmt = lds_mt[0] + lds_mt[1] + lds_mt[2] + lds_mt[3];

        double BN = (double)(BB * NN);
        double loss = (tce / BN) * (tfo / BN);
        double dice = 1.0 - 2.0 * ((double)tmt + 1.0) / (2.0 * BN + 1.0);
        double S = 2.0 * tpr;                    // full matrix sum (diag = 0)
        double mean_pred = S / (BN * (double)NN);
        double dml = 0.05 * log(0.05) - 0.05 * mean_pred;
        out[0] = (float)(loss + dice + dml);
    }
}

extern "C" void kernel_launch(void* const* d_in, const int* in_sizes, int n_in,
                              void* d_out, int out_size, void* d_ws, size_t ws_size,
                              hipStream_t stream)
{
    const float* pred        = (const float*)d_in[0];
    // d_in[1] = y_ohe: unused — the double-where provably collapses dis_map to 0.05
    const int*   targets     = (const int*)d_in[2];
    const int*   pred_choice = (const int*)d_in[3];

    char* ws = (char*)d_ws;
    size_t off = 0;
    unsigned short* p16 = (unsigned short*)ws;               // BB*NN*RP ushorts
    off += (size_t)BB * NN * RP * sizeof(unsigned short);
    off = (off + 127) & ~(size_t)127;
    float2* part_row = (float2*)(ws + off);                  // ROWBLK float2
    off += (size_t)ROWBLK * sizeof(float2);
    int* part_match = (int*)(ws + off);                      // ROWBLK int
    off += (size_t)ROWBLK * sizeof(int);
    off = (off + 127) & ~(size_t)127;
    float* slotf = (float*)(ws + off);                       // 64 slots x 128 B
    off += (size_t)NSLOT * SLOTSTR * sizeof(float);
    unsigned* subcnt = (unsigned*)(ws + off);                // 64 counters x 128 B
    off += (size_t)NSLOT * SLOTSTR * sizeof(unsigned);
    unsigned* master = (unsigned*)(ws + off);
    off += sizeof(unsigned);

    row_kernel<<<ROWBLK, 256, 0, stream>>>(pred, targets, pred_choice,
                                           p16, part_row, part_match,
                                           slotf, subcnt, master);
    pair_kernel<<<PAIRBLK, 256, 0, stream>>>(p16, part_row, part_match,
                                             slotf, subcnt, master, (float*)d_out);
}

// Round 16
// 20.646 us; speedup vs baseline: 1.0237x; 1.0237x over previous
//
#include <hip/hip_runtime.h>
#include <math.h>

#define BB 2
#define NN 4096
#define CC 33
#define RP 40                         // bf16 row pitch in ushorts (80 B): probs 0..32,
                                      // pad 33, sqn f32 in 34..35, pad 36..39
#define TILE 64
#define NTILES (NN / TILE)            // 64
#define NJT 4                         // j-tiles per block
#define NPB 544                       // sum over ti of ceil((64-ti)/4)
#define ROWBLK 256                    // 256 blocks x 32 rows (8 rows/wave, 8 lanes/row)
#define PAIRBLK (BB * NPB)            // 1088 pair blocks
#define NSLOT 64
#define SLOTSTR 32                    // 128 B between slots (distinct L2 lines)

typedef __attribute__((ext_vector_type(8))) short frag_ab;   // 8 bf16 (4 VGPRs)
typedef __attribute__((ext_vector_type(4))) float f32x4;     // 4 fp32 accum

__device__ __forceinline__ float fast_sqrt(float x) {
    return __builtin_amdgcn_sqrtf(x);                        // v_sqrt_f32, ~2 ULP
}
__device__ __forceinline__ unsigned f2bf(float x) {          // RNE, x >= 0 finite
    unsigned u = __float_as_uint(x);
    return (u + 0x7FFFu + ((u >> 16) & 1u)) >> 16;
}
__device__ __forceinline__ float bf2f(unsigned b) {
    return __uint_as_float(b << 16);
}

// ---------------- kernel 1: softmax, 8 rows/wave (8 lanes x 4 classes each;
// class 32 on group leader). sqn packed into row pad (ushorts 34..35).
__global__ __launch_bounds__(256) void row_kernel(
    const float* __restrict__ pred, const int* __restrict__ targets,
    const int* __restrict__ pred_choice, unsigned short* __restrict__ p16,
    float2* __restrict__ part_row, int* __restrict__ part_match,
    float* __restrict__ slotf, unsigned* __restrict__ subcnt,
    unsigned* __restrict__ master)
{
    __shared__ __align__(16) float sraw[32 * CC];     // 4.2 KB
    __shared__ float2 lds_cf[4];
    __shared__ int lds_mt[4];

    if (blockIdx.x == 0) {
        for (int i = threadIdx.x; i < NSLOT * SLOTSTR; i += 256) {
            slotf[i] = 0.0f;
            subcnt[i] = 0u;
        }
        if (threadIdx.x == 0) *master = 0u;
    }

    {   // flat coalesced staging: 32 rows = 1056 floats = 264 float4 (aligned)
        const float4* src = (const float4*)(pred + (size_t)blockIdx.x * 32 * CC);
        float4* dst = (float4*)sraw;
        for (int k = threadIdx.x; k < 264; k += 256) dst[k] = src[k];
    }
    __syncthreads();

    int l = threadIdx.x & 63;
    int w = threadIdx.x >> 6;
    int r = l >> 3;                    // row within wave (0..7)
    int c = l & 7;                     // class chunk: classes 4c..4c+3
    int rloc = w * 8 + r;              // row within block (0..31)
    int row = blockIdx.x * 32 + rloc;

    float v[4];
    #pragma unroll
    for (int k = 0; k < 4; k++) v[k] = sraw[rloc * CC + 4 * c + k];
    float v32 = sraw[rloc * CC + 32];

    float m = fmaxf(fmaxf(v[0], v[1]), fmaxf(v[2], v[3]));
    if (c == 0) m = fmaxf(m, v32);
    m = fmaxf(m, __shfl_xor(m, 1));
    m = fmaxf(m, __shfl_xor(m, 2));
    m = fmaxf(m, __shfl_xor(m, 4));

    float e[4];
    float s = 0.0f;
    #pragma unroll
    for (int k = 0; k < 4; k++) { e[k] = __expf(v[k] - m); s += e[k]; }
    float e32 = __expf(v32 - m);
    if (c == 0) s += e32;
    s += __shfl_xor(s, 1);
    s += __shfl_xor(s, 2);
    s += __shfl_xor(s, 4);
    float inv = 1.0f / s;

    // pack rounded bf16 probs + sqn in ROUNDED space
    unsigned pb[4];
    float sq = 0.0f;
    #pragma unroll
    for (int k = 0; k < 4; k++) {
        pb[k] = f2bf(e[k] * inv);
        float pf = bf2f(pb[k]);
        sq += pf * pf;
    }
    unsigned c32u = f2bf(e32 * inv);
    float c32 = bf2f(c32u);
    if (c == 0) sq += c32 * c32;
    sq += __shfl_xor(sq, 1);
    sq += __shfl_xor(sq, 2);
    sq += __shfl_xor(sq, 4);

    {   // 8B packed store: classes 4c..4c+3
        uint2 st = make_uint2(pb[0] | (pb[1] << 16), pb[2] | (pb[3] << 16));
        *(uint2*)&p16[(size_t)row * RP + 4 * c] = st;
    }
    if (c == 0) {                      // ushorts 32..39: c32, 0, sq(f32), 0, 0
        uint4 st = make_uint4(c32u, __float_as_uint(sq), 0u, 0u);
        *(uint4*)&p16[(size_t)row * RP + 32] = st;
    }

    // CE / focal / match (raw-space prob of target class)
    int tg = targets[row];
    float cand = 0.0f;
    if (tg < 32) {
        int cc = tg >> 2, kk = tg & 3;
        if (cc == c) cand = e[kk];
    } else if (c == 0) cand = e32;
    cand += __shfl_xor(cand, 1);
    cand += __shfl_xor(cand, 2);
    cand += __shfl_xor(cand, 4);

    float ce = 0.0f, fo = 0.0f; int mt = 0;
    if (c == 0) {
        float pt = cand * inv;
        ce = -__logf(pt);
        float om = 1.0f - pt;
        fo = om * om;
        mt = (tg == pred_choice[row]) ? 1 : 0;
    }
    ce += __shfl_xor(ce, 8);  ce += __shfl_xor(ce, 16);  ce += __shfl_xor(ce, 32);
    fo += __shfl_xor(fo, 8);  fo += __shfl_xor(fo, 16);  fo += __shfl_xor(fo, 32);
    mt += __shfl_xor(mt, 8);  mt += __shfl_xor(mt, 16);  mt += __shfl_xor(mt, 32);

    if (l == 0) { lds_cf[w] = make_float2(ce, fo); lds_mt[w] = mt; }
    __syncthreads();
    if (threadIdx.x == 0) {
        float2 a = lds_cf[0], b2 = lds_cf[1], c2 = lds_cf[2], d = lds_cf[3];
        part_row[blockIdx.x] = make_float2(a.x + b2.x + c2.x + d.x,
                                           a.y + b2.y + c2.y + d.y);
        part_match[blockIdx.x] = lds_mt[0] + lds_mt[1] + lds_mt[2] + lds_mt[3];
    }
}

// ---------------- kernel 2: 64x256 Gram tiles via bf16 MFMA. One i-tile x
// up to 4 j-tiles per block (A-frag reused x16 MFMAs). sqn from the row pad.
// Fence-free 64-slot completion protocol (uneven counts 17); winner block
// finalizes.
__global__ __launch_bounds__(256) void pair_kernel(
    const unsigned short* __restrict__ p16,
    const float2* __restrict__ part_row, const int* __restrict__ part_match,
    float* __restrict__ slotf, unsigned* __restrict__ subcnt,
    unsigned* __restrict__ master, float* __restrict__ out)
{
    __shared__ __align__(16) unsigned short spi[TILE * RP];
    __shared__ __align__(16) unsigned short spj[NJT * TILE * RP];
    __shared__ float red[4];
    __shared__ int lastFlag;
    __shared__ double lds_ce[4], lds_fo[4], lds_pr[4];
    __shared__ int lds_mt[4];

    int bid = blockIdx.x;
    int b = bid / NPB;
    int t = bid % NPB;

    // decode: row ti has ceil((64-ti)/NJT) blocks (block-uniform scalar loop)
    int ti = 0, rem = t;
    while (rem >= (NTILES - ti + NJT - 1) / NJT) {
        rem -= (NTILES - ti + NJT - 1) / NJT; ++ti;
    }
    int tjA = ti + NJT * rem;
    int avail = NTILES - tjA; if (avail > NJT) avail = NJT;
    bool diagA = (tjA == ti);
    int i0 = ti * TILE, j0A = tjA * TILE;

    // linear staging: i-tile + avail j-tiles, all contiguous 5120B chunks
    {
        const float4* srci = (const float4*)(p16 + ((size_t)b * NN + i0) * RP);
        const float4* srcj = (const float4*)(p16 + ((size_t)b * NN + j0A) * RP);
        float4* di = (float4*)spi;
        float4* dj = (float4*)spj;
        int jf4 = avail * 320;
        for (int k = threadIdx.x; k < 320; k += 256) di[k] = srci[k];
        for (int k = threadIdx.x; k < jf4; k += 256) dj[k] = srcj[k];
    }
    __syncthreads();

    int l = threadIdx.x & 63;
    int w = threadIdx.x >> 6;          // wave = 16-row strip of the i-tile
    int col = l & 15;
    int kc = l >> 4;                   // k-chunk 0..3 (8 bf16 each)

    // A fragment: rows 16w..16w+15 of i-tile, k = kc*8..kc*8+7 (reused x16)
    frag_ab afr = *(const frag_ab*)&spi[(16 * w + col) * RP + kc * 8];

    // per-lane row metadata from the row pad (C layout rows 16w+kc*4+r)
    float qi[4], c32a[4];
    #pragma unroll
    for (int r = 0; r < 4; r++) {
        int ir = 16 * w + kc * 4 + r;
        qi[r]   = __uint_as_float(*(const unsigned*)&spi[ir * RP + 34]);
        c32a[r] = bf2f(spi[ir * RP + 32]);
    }
    int gi0 = i0 + 16 * w + kc * 4;    // gi = gi0 + r

    float ssum = 0.0f;

    #pragma unroll
    for (int jt = 0; jt < NJT; jt++) {
        if (jt >= avail) break;                      // block-uniform
        const unsigned short* spjx = spj + jt * TILE * RP;
        int j0 = j0A + jt * TILE;
        bool dg = (jt == 0) && diagA;

        #pragma unroll
        for (int n = 0; n < 4; n++) {  // 16-col subtiles of this j-tile
            int jr = 16 * n + col;
            frag_ab bfr = *(const frag_ab*)&spjx[jr * RP + kc * 8];
            f32x4 acc = {0.0f, 0.0f, 0.0f, 0.0f};
            acc = __builtin_amdgcn_mfma_f32_16x16x32_bf16(afr, bfr, acc, 0, 0, 0);

            float c32b = bf2f(spjx[jr * RP + 32]);
            float qj   = __uint_as_float(*(const unsigned*)&spjx[jr * RP + 34]);
            int   gj   = j0 + 16 * n + col;

            #pragma unroll
            for (int r = 0; r < 4; r++) {
                float g  = fmaf(c32a[r], c32b, acc[r]);      // + class-32 term
                float d2 = fmaf(-2.0f, g, qi[r] + qj);
                float d  = fast_sqrt(fmaxf(d2, 0.0f));
                ssum += (!dg || gj > gi0 + r) ? d : 0.0f;    // strict upper on diag
            }
        }
    }

    #pragma unroll
    for (int off = 32; off; off >>= 1) ssum += __shfl_xor(ssum, off);
    if (l == 0) red[w] = ssum;
    __syncthreads();

    if (threadIdx.x == 0) {
        float blockSum = red[0] + red[1] + red[2] + red[3];
        int slotIdx = bid & (NSLOT - 1);
        int slot = slotIdx * SLOTSTR;
        unsigned expect = (unsigned)(PAIRBLK / NSLOT) + (slotIdx < (PAIRBLK % NSLOT) ? 1u : 0u);
        __hip_atomic_fetch_add(&slotf[slot], blockSum,
                               __ATOMIC_RELAXED, __HIP_MEMORY_SCOPE_AGENT);
        asm volatile("s_waitcnt vmcnt(0)" ::: "memory");   // order fadd before count
        unsigned o = __hip_atomic_fetch_add(&subcnt[slot], 1u,
                                            __ATOMIC_RELAXED, __HIP_MEMORY_SCOPE_AGENT);
        int last = 0;
        if (o == expect - 1) {                             // last block of this slot
            unsigned o2 = __hip_atomic_fetch_add(master, 1u,
                                                 __ATOMIC_RELAXED, __HIP_MEMORY_SCOPE_AGENT);
            last = (o2 == NSLOT - 1);
        }
        lastFlag = last;
    }
    __syncthreads();
    if (!lastFlag) return;

    // ---- fused finalize (winner block only; slots coherent via agent atomics,
    //      part_* via kernel-boundary) ----
    double ce = 0.0, fo = 0.0, pr = 0.0;
    int mt = 0;
    for (int i = threadIdx.x; i < ROWBLK; i += 256) {
        float2 v = part_row[i];
        ce += (double)v.x;
        fo += (double)v.y;
        mt += part_match[i];
    }
    for (int i = threadIdx.x; i < NSLOT; i += 256)
        pr += (double)__hip_atomic_load(&slotf[i * SLOTSTR],
                                        __ATOMIC_RELAXED, __HIP_MEMORY_SCOPE_AGENT);

    #pragma unroll
    for (int off = 32; off; off >>= 1) {
        ce += __shfl_xor(ce, off);
        fo += __shfl_xor(fo, off);
        pr += __shfl_xor(pr, off);
        mt += __shfl_xor(mt, off);
    }
    if (l == 0) { lds_ce[w] = ce; lds_fo[w] = fo; lds_pr[w] = pr; lds_mt[w] = mt; }
    __syncthreads();
    if (threadIdx.x == 0) {
        double tce = lds_ce[0] + lds_ce[1] + lds_ce[2] + lds_ce[3];
        double tfo = lds_fo[0] + lds_fo[1] + lds_fo[2] + lds_fo[3];
        double tpr = lds_pr[0] + lds_pr[1] + lds_pr[2] + lds_pr[3];
        int    tmt = lds_mt[0] + lds_mt[1] + lds_mt[2] + lds_mt[3];

        double BN = (double)(BB * NN);
        double loss = (tce / BN) * (tfo / BN);
        double dice = 1.0 - 2.0 * ((double)tmt + 1.0) / (2.0 * BN + 1.0);
        double S = 2.0 * tpr;                    // full matrix sum (diag = 0)
        double mean_pred = S / (BN * (double)NN);
        double dml = 0.05 * log(0.05) - 0.05 * mean_pred;
        out[0] = (float)(loss + dice + dml);
    }
}

extern "C" void kernel_launch(void* const* d_in, const int* in_sizes, int n_in,
                              void* d_out, int out_size, void* d_ws, size_t ws_size,
                              hipStream_t stream)
{
    const float* pred        = (const float*)d_in[0];
    // d_in[1] = y_ohe: unused — the double-where provably collapses dis_map to 0.05
    const int*   targets     = (const int*)d_in[2];
    const int*   pred_choice = (const int*)d_in[3];

    char* ws = (char*)d_ws;
    size_t off = 0;
    unsigned short* p16 = (unsigned short*)ws;               // BB*NN*RP ushorts
    off += (size_t)BB * NN * RP * sizeof(unsigned short);
    off = (off + 127) & ~(size_t)127;
    float2* part_row = (float2*)(ws + off);                  // ROWBLK float2
    off += (size_t)ROWBLK * sizeof(float2);
    int* part_match = (int*)(ws + off);                      // ROWBLK int
    off += (size_t)ROWBLK * sizeof(int);
    off = (off + 127) & ~(size_t)127;
    float* slotf = (float*)(ws + off);                       // 64 slots x 128 B
    off += (size_t)NSLOT * SLOTSTR * sizeof(float);
    unsigned* subcnt = (unsigned*)(ws + off);                // 64 counters x 128 B
    off += (size_t)NSLOT * SLOTSTR * sizeof(unsigned);
    unsigned* master = (unsigned*)(ws + off);
    off += sizeof(unsigned);

    row_kernel<<<ROWBLK, 256, 0, stream>>>(pred, targets, pred_choice,
                                           p16, part_row, part_match,
                                           slotf, subcnt, master);
    pair_kernel<<<PAIRBLK, 256, 0, stream>>>(p16, part_row, part_match,
                                             slotf, subcnt, master, (float*)d_out);
}

// Round 17
// 19.397 us; speedup vs baseline: 1.0896x; 1.0644x over previous
//
#include <hip/hip_runtime.h>
#include <math.h>

#define BB 2
#define NN 4096
#define CC 33
#define RP 40                         // bf16 row pitch in ushorts (80 B): probs 0..32,
                                      // pad 33, sqn f32 in 34..35, pad 36..39
#define TILE 64
#define NTILES (NN / TILE)            // 64
#define NJT 3                         // j-tiles per block (R14-proven optimum)
#define NPB 715                       // sum over ti of ceil((64-ti)/3)
#define ROWBLK 256                    // 256 blocks x 32 rows (8 rows/wave, 8 lanes/row)
#define PAIRBLK (BB * NPB)            // 1430 pair blocks
#define NSLOT 64
#define SLOTSTR 32                    // 128 B between slots (distinct L2 lines)

#define AS1 __attribute__((address_space(1)))
#define AS3 __attribute__((address_space(3)))

typedef __attribute__((ext_vector_type(8))) short frag_ab;   // 8 bf16 (4 VGPRs)
typedef __attribute__((ext_vector_type(4))) float f32x4;     // 4 fp32 accum

__device__ __forceinline__ float fast_sqrt(float x) {
    return __builtin_amdgcn_sqrtf(x);                        // v_sqrt_f32, ~2 ULP
}
__device__ __forceinline__ unsigned f2bf(float x) {          // RNE, x >= 0 finite
    unsigned u = __float_as_uint(x);
    return (u + 0x7FFFu + ((u >> 16) & 1u)) >> 16;
}
__device__ __forceinline__ float bf2f(unsigned b) {
    return __uint_as_float(b << 16);
}

// ---------------- kernel 1: softmax, 8 rows/wave (8 lanes x 4 classes each;
// class 32 on group leader). sqn packed into row pad (ushorts 34..35).
__global__ __launch_bounds__(256) void row_kernel(
    const float* __restrict__ pred, const int* __restrict__ targets,
    const int* __restrict__ pred_choice, unsigned short* __restrict__ p16,
    float2* __restrict__ part_row, int* __restrict__ part_match,
    float* __restrict__ slotf, unsigned* __restrict__ subcnt,
    unsigned* __restrict__ master)
{
    __shared__ __align__(16) float sraw[32 * CC];     // 4.2 KB
    __shared__ float2 lds_cf[4];
    __shared__ int lds_mt[4];

    if (blockIdx.x == 0) {
        for (int i = threadIdx.x; i < NSLOT * SLOTSTR; i += 256) {
            slotf[i] = 0.0f;
            subcnt[i] = 0u;
        }
        if (threadIdx.x == 0) *master = 0u;
    }

    {   // flat coalesced staging: 32 rows = 1056 floats = 264 float4 (aligned)
        const float4* src = (const float4*)(pred + (size_t)blockIdx.x * 32 * CC);
        float4* dst = (float4*)sraw;
        for (int k = threadIdx.x; k < 264; k += 256) dst[k] = src[k];
    }
    __syncthreads();

    int l = threadIdx.x & 63;
    int w = threadIdx.x >> 6;
    int r = l >> 3;                    // row within wave (0..7)
    int c = l & 7;                     // class chunk: classes 4c..4c+3
    int rloc = w * 8 + r;              // row within block (0..31)
    int row = blockIdx.x * 32 + rloc;

    float v[4];
    #pragma unroll
    for (int k = 0; k < 4; k++) v[k] = sraw[rloc * CC + 4 * c + k];
    float v32 = sraw[rloc * CC + 32];

    float m = fmaxf(fmaxf(v[0], v[1]), fmaxf(v[2], v[3]));
    if (c == 0) m = fmaxf(m, v32);
    m = fmaxf(m, __shfl_xor(m, 1));
    m = fmaxf(m, __shfl_xor(m, 2));
    m = fmaxf(m, __shfl_xor(m, 4));

    float e[4];
    float s = 0.0f;
    #pragma unroll
    for (int k = 0; k < 4; k++) { e[k] = __expf(v[k] - m); s += e[k]; }
    float e32 = __expf(v32 - m);
    if (c == 0) s += e32;
    s += __shfl_xor(s, 1);
    s += __shfl_xor(s, 2);
    s += __shfl_xor(s, 4);
    float inv = 1.0f / s;

    // pack rounded bf16 probs + sqn in ROUNDED space
    unsigned pb[4];
    float sq = 0.0f;
    #pragma unroll
    for (int k = 0; k < 4; k++) {
        pb[k] = f2bf(e[k] * inv);
        float pf = bf2f(pb[k]);
        sq += pf * pf;
    }
    unsigned c32u = f2bf(e32 * inv);
    float c32 = bf2f(c32u);
    if (c == 0) sq += c32 * c32;
    sq += __shfl_xor(sq, 1);
    sq += __shfl_xor(sq, 2);
    sq += __shfl_xor(sq, 4);

    {   // 8B packed store: classes 4c..4c+3
        uint2 st = make_uint2(pb[0] | (pb[1] << 16), pb[2] | (pb[3] << 16));
        *(uint2*)&p16[(size_t)row * RP + 4 * c] = st;
    }
    if (c == 0) {                      // ushorts 32..39: c32, 0, sq(f32), 0, 0
        uint4 st = make_uint4(c32u, __float_as_uint(sq), 0u, 0u);
        *(uint4*)&p16[(size_t)row * RP + 32] = st;
    }

    // CE / focal / match (raw-space prob of target class)
    int tg = targets[row];
    float cand = 0.0f;
    if (tg < 32) {
        int cc = tg >> 2, kk = tg & 3;
        if (cc == c) cand = e[kk];
    } else if (c == 0) cand = e32;
    cand += __shfl_xor(cand, 1);
    cand += __shfl_xor(cand, 2);
    cand += __shfl_xor(cand, 4);

    float ce = 0.0f, fo = 0.0f; int mt = 0;
    if (c == 0) {
        float pt = cand * inv;
        ce = -__logf(pt);
        float om = 1.0f - pt;
        fo = om * om;
        mt = (tg == pred_choice[row]) ? 1 : 0;
    }
    ce += __shfl_xor(ce, 8);  ce += __shfl_xor(ce, 16);  ce += __shfl_xor(ce, 32);
    fo += __shfl_xor(fo, 8);  fo += __shfl_xor(fo, 16);  fo += __shfl_xor(fo, 32);
    mt += __shfl_xor(mt, 8);  mt += __shfl_xor(mt, 16);  mt += __shfl_xor(mt, 32);

    if (l == 0) { lds_cf[w] = make_float2(ce, fo); lds_mt[w] = mt; }
    __syncthreads();
    if (threadIdx.x == 0) {
        float2 a = lds_cf[0], b2 = lds_cf[1], c2 = lds_cf[2], d = lds_cf[3];
        part_row[blockIdx.x] = make_float2(a.x + b2.x + c2.x + d.x,
                                           a.y + b2.y + c2.y + d.y);
        part_match[blockIdx.x] = lds_mt[0] + lds_mt[1] + lds_mt[2] + lds_mt[3];
    }
}

// ---------------- kernel 2: 64x192 Gram tiles via bf16 MFMA.
// A-side (i-tile): zero-reuse -> read fragment + metadata DIRECTLY from
// global (L2-resident), no LDS round-trip. B-side (j-tiles, 4x wave reuse):
// async global_load_lds width=16 staging (wave-uniform base + lane*16).
// Fence-free 64-slot completion protocol; winner block finalizes.
__global__ __launch_bounds__(256) void pair_kernel(
    const unsigned short* __restrict__ p16,
    const float2* __restrict__ part_row, const int* __restrict__ part_match,
    float* __restrict__ slotf, unsigned* __restrict__ subcnt,
    unsigned* __restrict__ master, float* __restrict__ out)
{
    __shared__ __align__(16) unsigned short spj[NJT * TILE * RP];  // 15 KB
    __shared__ float red[4];
    __shared__ int lastFlag;
    __shared__ double lds_ce[4], lds_fo[4], lds_pr[4];
    __shared__ int lds_mt[4];

    int bid = blockIdx.x;
    int b = bid / NPB;
    int t = bid % NPB;

    // decode: row ti has ceil((64-ti)/NJT) blocks (block-uniform scalar loop)
    int ti = 0, rem = t;
    while (rem >= (NTILES - ti + NJT - 1) / NJT) {
        rem -= (NTILES - ti + NJT - 1) / NJT; ++ti;
    }
    int tjA = ti + NJT * rem;
    int avail = NTILES - tjA; if (avail > NJT) avail = NJT;
    bool diagA = (tjA == ti);
    int i0 = ti * TILE, j0A = tjA * TILE;

    int l = threadIdx.x & 63;
    int w = threadIdx.x >> 6;          // wave = 16-row strip of the i-tile
    int col = l & 15;
    int kc = l >> 4;                   // k-chunk 0..3 (8 bf16 each)

    const unsigned short* pb16 = p16 + (size_t)b * NN * RP;

    // ---- issue async j-tile staging first: avail*5 chunks of 64 float4
    //      (lane l -> LDS base + l*16: exactly global_load_lds's pattern)
    {
        const float4* srcj = (const float4*)(pb16 + (size_t)j0A * RP);
        int nchunk = avail * 5;
        for (int c = w; c < nchunk; c += 4) {
            const float4* g = srcj + c * 64 + l;
            __builtin_amdgcn_global_load_lds(
                (const AS1 void*)g,
                (AS3 void*)((char*)spj + c * 1024),
                16, 0, 0);
        }
    }

    // ---- A-side direct from global (each byte read exactly once -> no LDS)
    int arow = i0 + 16 * w + col;
    frag_ab afr = *(const frag_ab*)&pb16[(size_t)arow * RP + kc * 8];

    float qi[4], c32a[4];
    #pragma unroll
    for (int r = 0; r < 4; r++) {
        int ir = i0 + 16 * w + kc * 4 + r;
        qi[r]   = __uint_as_float(*(const unsigned*)&pb16[(size_t)ir * RP + 34]);
        c32a[r] = bf2f(pb16[(size_t)ir * RP + 32]);
    }
    int gi0 = i0 + 16 * w + kc * 4;    // gi = gi0 + r

    __syncthreads();                   // drains vmcnt -> j-tiles resident in LDS

    float ssum = 0.0f;

    #pragma unroll
    for (int jt = 0; jt < NJT; jt++) {
        if (jt >= avail) break;                      // block-uniform
        const unsigned short* spjx = spj + jt * TILE * RP;
        int j0 = j0A + jt * TILE;
        bool dg = (jt == 0) && diagA;

        #pragma unroll
        for (int n = 0; n < 4; n++) {  // 16-col subtiles of this j-tile
            int jr = 16 * n + col;
            frag_ab bfr = *(const frag_ab*)&spjx[jr * RP + kc * 8];
            f32x4 acc = {0.0f, 0.0f, 0.0f, 0.0f};
            acc = __builtin_amdgcn_mfma_f32_16x16x32_bf16(afr, bfr, acc, 0, 0, 0);

            float c32b = bf2f(spjx[jr * RP + 32]);
            float qj   = __uint_as_float(*(const unsigned*)&spjx[jr * RP + 34]);
            int   gj   = j0 + 16 * n + col;

            #pragma unroll
            for (int r = 0; r < 4; r++) {
                float g  = fmaf(c32a[r], c32b, acc[r]);      // + class-32 term
                float d2 = fmaf(-2.0f, g, qi[r] + qj);
                float d  = fast_sqrt(fmaxf(d2, 0.0f));
                ssum += (!dg || gj > gi0 + r) ? d : 0.0f;    // strict upper on diag
            }
        }
    }

    #pragma unroll
    for (int off = 32; off; off >>= 1) ssum += __shfl_xor(ssum, off);
    if (l == 0) red[w] = ssum;
    __syncthreads();

    if (threadIdx.x == 0) {
        float blockSum = red[0] + red[1] + red[2] + red[3];
        int slotIdx = bid & (NSLOT - 1);
        int slot = slotIdx * SLOTSTR;
        unsigned expect = (unsigned)(PAIRBLK / NSLOT) + (slotIdx < (PAIRBLK % NSLOT) ? 1u : 0u);
        __hip_atomic_fetch_add(&slotf[slot], blockSum,
                               __ATOMIC_RELAXED, __HIP_MEMORY_SCOPE_AGENT);
        asm volatile("s_waitcnt vmcnt(0)" ::: "memory");   // order fadd before count
        unsigned o = __hip_atomic_fetch_add(&subcnt[slot], 1u,
                                            __ATOMIC_RELAXED, __HIP_MEMORY_SCOPE_AGENT);
        int last = 0;
        if (o == expect - 1) {                             // last block of this slot
            unsigned o2 = __hip_atomic_fetch_add(master, 1u,
                                                 __ATOMIC_RELAXED, __HIP_MEMORY_SCOPE_AGENT);
            last = (o2 == NSLOT - 1);
        }
        lastFlag = last;
    }
    __syncthreads();
    if (!lastFlag) return;

    // ---- fused finalize (winner block only; slots coherent via agent atomics,
    //      part_* via kernel-boundary) ----
    double ce = 0.0, fo = 0.0, pr = 0.0;
    int mt = 0;
    for (int i = threadIdx.x; i < ROWBLK; i += 256) {
        float2 v = part_row[i];
        ce += (double)v.x;
        fo += (double)v.y;
        mt += part_match[i];
    }
    for (int i = threadIdx.x; i < NSLOT; i += 256)
        pr += (double)__hip_atomic_load(&slotf[i * SLOTSTR],
                                        __ATOMIC_RELAXED, __HIP_MEMORY_SCOPE_AGENT);

    #pragma unroll
    for (int off = 32; off; off >>= 1) {
        ce += __shfl_xor(ce, off);
        fo += __shfl_xor(fo, off);
        pr += __shfl_xor(pr, off);
        mt += __shfl_xor(mt, off);
    }
    if (l == 0) { lds_ce[w] = ce; lds_fo[w] = fo; lds_pr[w] = pr; lds_mt[w] = mt; }
    __syncthreads();
    if (threadIdx.x == 0) {
        double tce = lds_ce[0] + lds_ce[1] + lds_ce[2] + lds_ce[3];
        double tfo = lds_fo[0] + lds_fo[1] + lds_fo[2] + lds_fo[3];
        double tpr = lds_pr[0] + lds_pr[1] + lds_pr[2] + lds_pr[3];
        int    tmt = lds_mt[0] + lds_mt[1] + lds_mt[2] + lds_mt[3];

        double BN = (double)(BB * NN);
        double loss = (tce / BN) * (tfo / BN);
        double dice = 1.0 - 2.0 * ((double)tmt + 1.0) / (2.0 * BN + 1.0);
        double S = 2.0 * tpr;                    // full matrix sum (diag = 0)
        double mean_pred = S / (BN * (double)NN);
        double dml = 0.05 * log(0.05) - 0.05 * mean_pred;
        out[0] = (float)(loss + dice + dml);
    }
}

extern "C" void kernel_launch(void* const* d_in, const int* in_sizes, int n_in,
                              void* d_out, int out_size, void* d_ws, size_t ws_size,
                              hipStream_t stream)
{
    const float* pred        = (const float*)d_in[0];
    // d_in[1] = y_ohe: unused — the double-where provably collapses dis_map to 0.05
    const int*   targets     = (const int*)d_in[2];
    const int*   pred_choice = (const int*)d_in[3];

    char* ws = (char*)d_ws;
    size_t off = 0;
    unsigned short* p16 = (unsigned short*)ws;               // BB*NN*RP ushorts
    off += (size_t)BB * NN * RP * sizeof(unsigned short);
    off = (off + 127) & ~(size_t)127;
    float2* part_row = (float2*)(ws + off);                  // ROWBLK float2
    off += (size_t)ROWBLK * sizeof(float2);
    int* part_match = (int*)(ws + off);                      // ROWBLK int
    off += (size_t)ROWBLK * sizeof(int);
    off = (off + 127) & ~(size_t)127;
    float* slotf = (float*)(ws + off);                       // 64 slots x 128 B
    off += (size_t)NSLOT * SLOTSTR * sizeof(float);
    unsigned* subcnt = (unsigned*)(ws + off);                // 64 counters x 128 B
    off += (size_t)NSLOT * SLOTSTR * sizeof(unsigned);
    unsigned* master = (unsigned*)(ws + off);
    off += sizeof(unsigned);

    row_kernel<<<ROWBLK, 256, 0, stream>>>(pred, targets, pred_choice,
                                           p16, part_row, part_match,
                                           slotf, subcnt, master);
    pair_kernel<<<PAIRBLK, 256, 0, stream>>>(p16, part_row, part_match,
                                             slotf, subcnt, master, (float*)d_out);
}

// Round 18
// 19.372 us; speedup vs baseline: 1.0910x; 1.0013x over previous
//
#include <hip/hip_runtime.h>
#include <math.h>

#define BB 2
#define NN 4096
#define CC 33
#define RP 40                         // bf16 row pitch in ushorts (80 B): probs 0..32,
                                      // pad 33, sqn f32 in 34..35, pad 36..39
#define TILE 64
#define NTILES (NN / TILE)            // 64
#define NJT 3                         // j-tiles per block (R14-proven optimum)
#define NPB 715                       // sum over ti of ceil((64-ti)/3)
#define ROWBLK 256                    // 256 blocks x 32 rows (8 rows/wave, 8 lanes/row)
#define PAIRBLK (BB * NPB)            // 1430 pair blocks
#define NSLOT 64
#define SLOTSTR 32                    // 128 B between slots (distinct L2 lines)

#define AS1 __attribute__((address_space(1)))
#define AS3 __attribute__((address_space(3)))

typedef __attribute__((ext_vector_type(8))) short frag_ab;   // 8 bf16 (4 VGPRs)
typedef __attribute__((ext_vector_type(4))) float f32x4;     // 4 fp32 accum

__device__ __forceinline__ float fast_sqrt(float x) {
    return __builtin_amdgcn_sqrtf(x);                        // v_sqrt_f32, ~2 ULP
}
__device__ __forceinline__ unsigned f2bf(float x) {          // RNE, x >= 0 finite
    unsigned u = __float_as_uint(x);
    return (u + 0x7FFFu + ((u >> 16) & 1u)) >> 16;
}
__device__ __forceinline__ float bf2f(unsigned b) {
    return __uint_as_float(b << 16);
}

// ---------------- kernel 1: softmax, 8 rows/wave (8 lanes x 4 classes each;
// class 32 on group leader). sqn packed into row pad (ushorts 34..35).
// Staging via async global_load_lds (4x 1KB chunks + 8-float4 tail).
__global__ __launch_bounds__(256) void row_kernel(
    const float* __restrict__ pred, const int* __restrict__ targets,
    const int* __restrict__ pred_choice, unsigned short* __restrict__ p16,
    float2* __restrict__ part_row, int* __restrict__ part_match,
    float* __restrict__ slotf, unsigned* __restrict__ subcnt,
    unsigned* __restrict__ master)
{
    __shared__ __align__(16) float sraw[32 * CC];     // 4.2 KB
    __shared__ float2 lds_cf[4];
    __shared__ int lds_mt[4];

    if (blockIdx.x == 0) {
        for (int i = threadIdx.x; i < NSLOT * SLOTSTR; i += 256) {
            slotf[i] = 0.0f;
            subcnt[i] = 0u;
        }
        if (threadIdx.x == 0) *master = 0u;
    }

    int l = threadIdx.x & 63;
    int w = threadIdx.x >> 6;

    {   // async staging: 1056 floats = 264 float4 = 4 x (64-lane x 16B) + 8 tail
        const float4* src = (const float4*)(pred + (size_t)blockIdx.x * 32 * CC);
        __builtin_amdgcn_global_load_lds(
            (const AS1 void*)(src + w * 64 + l),
            (AS3 void*)((char*)sraw + w * 1024), 16, 0, 0);
        if (threadIdx.x < 8) {
            float4 tv = src[256 + threadIdx.x];
            ((float4*)sraw)[256 + threadIdx.x] = tv;
        }
    }
    __syncthreads();

    int r = l >> 3;                    // row within wave (0..7)
    int c = l & 7;                     // class chunk: classes 4c..4c+3
    int rloc = w * 8 + r;              // row within block (0..31)
    int row = blockIdx.x * 32 + rloc;

    float v[4];
    #pragma unroll
    for (int k = 0; k < 4; k++) v[k] = sraw[rloc * CC + 4 * c + k];
    float v32 = sraw[rloc * CC + 32];

    float m = fmaxf(fmaxf(v[0], v[1]), fmaxf(v[2], v[3]));
    if (c == 0) m = fmaxf(m, v32);
    m = fmaxf(m, __shfl_xor(m, 1));
    m = fmaxf(m, __shfl_xor(m, 2));
    m = fmaxf(m, __shfl_xor(m, 4));

    float e[4];
    float s = 0.0f;
    #pragma unroll
    for (int k = 0; k < 4; k++) { e[k] = __expf(v[k] - m); s += e[k]; }
    float e32 = __expf(v32 - m);
    if (c == 0) s += e32;
    s += __shfl_xor(s, 1);
    s += __shfl_xor(s, 2);
    s += __shfl_xor(s, 4);
    float inv = 1.0f / s;

    // pack rounded bf16 probs + sqn in ROUNDED space
    unsigned pb[4];
    float sq = 0.0f;
    #pragma unroll
    for (int k = 0; k < 4; k++) {
        pb[k] = f2bf(e[k] * inv);
        float pf = bf2f(pb[k]);
        sq += pf * pf;
    }
    unsigned c32u = f2bf(e32 * inv);
    float c32 = bf2f(c32u);
    if (c == 0) sq += c32 * c32;
    sq += __shfl_xor(sq, 1);
    sq += __shfl_xor(sq, 2);
    sq += __shfl_xor(sq, 4);

    {   // 8B packed store: classes 4c..4c+3
        uint2 st = make_uint2(pb[0] | (pb[1] << 16), pb[2] | (pb[3] << 16));
        *(uint2*)&p16[(size_t)row * RP + 4 * c] = st;
    }
    if (c == 0) {                      // ushorts 32..39: c32, 0, sq(f32), 0, 0
        uint4 st = make_uint4(c32u, __float_as_uint(sq), 0u, 0u);
        *(uint4*)&p16[(size_t)row * RP + 32] = st;
    }

    // CE / focal / match (raw-space prob of target class)
    int tg = targets[row];
    float cand = 0.0f;
    if (tg < 32) {
        int cc = tg >> 2, kk = tg & 3;
        if (cc == c) cand = e[kk];
    } else if (c == 0) cand = e32;
    cand += __shfl_xor(cand, 1);
    cand += __shfl_xor(cand, 2);
    cand += __shfl_xor(cand, 4);

    float ce = 0.0f, fo = 0.0f; int mt = 0;
    if (c == 0) {
        float pt = cand * inv;
        ce = -__logf(pt);
        float om = 1.0f - pt;
        fo = om * om;
        mt = (tg == pred_choice[row]) ? 1 : 0;
    }
    ce += __shfl_xor(ce, 8);  ce += __shfl_xor(ce, 16);  ce += __shfl_xor(ce, 32);
    fo += __shfl_xor(fo, 8);  fo += __shfl_xor(fo, 16);  fo += __shfl_xor(fo, 32);
    mt += __shfl_xor(mt, 8);  mt += __shfl_xor(mt, 16);  mt += __shfl_xor(mt, 32);

    if (l == 0) { lds_cf[w] = make_float2(ce, fo); lds_mt[w] = mt; }
    __syncthreads();
    if (threadIdx.x == 0) {
        float2 a = lds_cf[0], b2 = lds_cf[1], c2 = lds_cf[2], d = lds_cf[3];
        part_row[blockIdx.x] = make_float2(a.x + b2.x + c2.x + d.x,
                                           a.y + b2.y + c2.y + d.y);
        part_match[blockIdx.x] = lds_mt[0] + lds_mt[1] + lds_mt[2] + lds_mt[3];
    }
}

// ---------------- kernel 2: 64x192 Gram tiles via bf16 MFMA.
// A-side direct from global (zero reuse); j-tiles via async global_load_lds.
// Metadata (c32 + sqn) fetched as ONE 8B load from the row pad (ushorts
// 32..35). Fence-free 64-slot completion protocol; winner block finalizes.
__global__ __launch_bounds__(256) void pair_kernel(
    const unsigned short* __restrict__ p16,
    const float2* __restrict__ part_row, const int* __restrict__ part_match,
    float* __restrict__ slotf, unsigned* __restrict__ subcnt,
    unsigned* __restrict__ master, float* __restrict__ out)
{
    __shared__ __align__(16) unsigned short spj[NJT * TILE * RP];  // 15 KB
    __shared__ float red[4];
    __shared__ int lastFlag;
    __shared__ double lds_ce[4], lds_fo[4], lds_pr[4];
    __shared__ int lds_mt[4];

    int bid = blockIdx.x;
    int b = bid / NPB;
    int t = bid % NPB;

    // decode: row ti has ceil((64-ti)/NJT) blocks (block-uniform scalar loop)
    int ti = 0, rem = t;
    while (rem >= (NTILES - ti + NJT - 1) / NJT) {
        rem -= (NTILES - ti + NJT - 1) / NJT; ++ti;
    }
    int tjA = ti + NJT * rem;
    int avail = NTILES - tjA; if (avail > NJT) avail = NJT;
    bool diagA = (tjA == ti);
    int i0 = ti * TILE, j0A = tjA * TILE;

    int l = threadIdx.x & 63;
    int w = threadIdx.x >> 6;          // wave = 16-row strip of the i-tile
    int col = l & 15;
    int kc = l >> 4;                   // k-chunk 0..3 (8 bf16 each)

    const unsigned short* pb16 = p16 + (size_t)b * NN * RP;

    // ---- issue async j-tile staging first: avail*5 chunks of 64 float4
    {
        const float4* srcj = (const float4*)(pb16 + (size_t)j0A * RP);
        int nchunk = avail * 5;
        for (int c = w; c < nchunk; c += 4) {
            const float4* g = srcj + c * 64 + l;
            __builtin_amdgcn_global_load_lds(
                (const AS1 void*)g,
                (AS3 void*)((char*)spj + c * 1024),
                16, 0, 0);
        }
    }

    // ---- A-side direct from global (each byte read exactly once -> no LDS)
    int arow = i0 + 16 * w + col;
    frag_ab afr = *(const frag_ab*)&pb16[(size_t)arow * RP + kc * 8];

    float qi[4], c32a[4];
    #pragma unroll
    for (int r = 0; r < 4; r++) {
        int ir = i0 + 16 * w + kc * 4 + r;
        uint2 md = *(const uint2*)&pb16[(size_t)ir * RP + 32];  // c32 | sq
        c32a[r] = bf2f(md.x);
        qi[r]   = __uint_as_float(md.y);
    }
    int gi0 = i0 + 16 * w + kc * 4;    // gi = gi0 + r

    __syncthreads();                   // drains vmcnt -> j-tiles resident in LDS

    float ssum = 0.0f;

    #pragma unroll
    for (int jt = 0; jt < NJT; jt++) {
        if (jt >= avail) break;                      // block-uniform
        const unsigned short* spjx = spj + jt * TILE * RP;
        int j0 = j0A + jt * TILE;
        bool dg = (jt == 0) && diagA;

        #pragma unroll
        for (int n = 0; n < 4; n++) {  // 16-col subtiles of this j-tile
            int jr = 16 * n + col;
            frag_ab bfr = *(const frag_ab*)&spjx[jr * RP + kc * 8];
            f32x4 acc = {0.0f, 0.0f, 0.0f, 0.0f};
            acc = __builtin_amdgcn_mfma_f32_16x16x32_bf16(afr, bfr, acc, 0, 0, 0);

            uint2 md = *(const uint2*)&spjx[jr * RP + 32];   // one ds_read_b64
            float c32b = bf2f(md.x);
            float qj   = __uint_as_float(md.y);
            int   gj   = j0 + 16 * n + col;

            #pragma unroll
            for (int r = 0; r < 4; r++) {
                float g  = fmaf(c32a[r], c32b, acc[r]);      // + class-32 term
                float d2 = fmaf(-2.0f, g, qi[r] + qj);
                float d  = fast_sqrt(fmaxf(d2, 0.0f));
                ssum += (!dg || gj > gi0 + r) ? d : 0.0f;    // strict upper on diag
            }
        }
    }

    #pragma unroll
    for (int off = 32; off; off >>= 1) ssum += __shfl_xor(ssum, off);
    if (l == 0) red[w] = ssum;
    __syncthreads();

    if (threadIdx.x == 0) {
        float blockSum = red[0] + red[1] + red[2] + red[3];
        int slotIdx = bid & (NSLOT - 1);
        int slot = slotIdx * SLOTSTR;
        unsigned expect = (unsigned)(PAIRBLK / NSLOT) + (slotIdx < (PAIRBLK % NSLOT) ? 1u : 0u);
        __hip_atomic_fetch_add(&slotf[slot], blockSum,
                               __ATOMIC_RELAXED, __HIP_MEMORY_SCOPE_AGENT);
        asm volatile("s_waitcnt vmcnt(0)" ::: "memory");   // order fadd before count
        unsigned o = __hip_atomic_fetch_add(&subcnt[slot], 1u,
                                            __ATOMIC_RELAXED, __HIP_MEMORY_SCOPE_AGENT);
        int last = 0;
        if (o == expect - 1) {                             // last block of this slot
            unsigned o2 = __hip_atomic_fetch_add(master, 1u,
                                                 __ATOMIC_RELAXED, __HIP_MEMORY_SCOPE_AGENT);
            last = (o2 == NSLOT - 1);
        }
        lastFlag = last;
    }
    __syncthreads();
    if (!lastFlag) return;

    // ---- fused finalize (winner block only; slots coherent via agent atomics,
    //      part_* via kernel-boundary) ----
    double ce = 0.0, fo = 0.0, pr = 0.0;
    int mt = 0;
    for (int i = threadIdx.x; i < ROWBLK; i += 256) {
        float2 v = part_row[i];
        ce += (double)v.x;
        fo += (double)v.y;
        mt += part_match[i];
    }
    for (int i = threadIdx.x; i < NSLOT; i += 256)
        pr += (double)__hip_atomic_load(&slotf[i * SLOTSTR],
                                        __ATOMIC_RELAXED, __HIP_MEMORY_SCOPE_AGENT);

    #pragma unroll
    for (int off = 32; off; off >>= 1) {
        ce += __shfl_xor(ce, off);
        fo += __shfl_xor(fo, off);
        pr += __shfl_xor(pr, off);
        mt += __shfl_xor(mt, off);
    }
    if (l == 0) { lds_ce[w] = ce; lds_fo[w] = fo; lds_pr[w] = pr; lds_mt[w] = mt; }
    __syncthreads();
    if (threadIdx.x == 0) {
        double tce = lds_ce[0] + lds_ce[1] + lds_ce[2] + lds_ce[3];
        double tfo = lds_fo[0] + lds_fo[1] + lds_fo[2] + lds_fo[3];
        double tpr = lds_pr[0] + lds_pr[1] + lds_pr[2] + lds_pr[3];
        int    tmt = lds_mt[0] + lds_mt[1] + lds_mt[2] + lds_mt[3];

        double BN = (double)(BB * NN);
        double loss = (tce / BN) * (tfo / BN);
        double dice = 1.0 - 2.0 * ((double)tmt + 1.0) / (2.0 * BN + 1.0);
        double S = 2.0 * tpr;                    // full matrix sum (diag = 0)
        double mean_pred = S / (BN * (double)NN);
        double dml = 0.05 * log(0.05) - 0.05 * mean_pred;
        out[0] = (float)(loss + dice + dml);
    }
}

extern "C" void kernel_launch(void* const* d_in, const int* in_sizes, int n_in,
                              void* d_out, int out_size, void* d_ws, size_t ws_size,
                              hipStream_t stream)
{
    const float* pred        = (const float*)d_in[0];
    // d_in[1] = y_ohe: unused — the double-where provably collapses dis_map to 0.05
    const int*   targets     = (const int*)d_in[2];
    const int*   pred_choice = (const int*)d_in[3];

    char* ws = (char*)d_ws;
    size_t off = 0;
    unsigned short* p16 = (unsigned short*)ws;               // BB*NN*RP ushorts
    off += (size_t)BB * NN * RP * sizeof(unsigned short);
    off = (off + 127) & ~(size_t)127;
    float2* part_row = (float2*)(ws + off);                  // ROWBLK float2
    off += (size_t)ROWBLK * sizeof(float2);
    int* part_match = (int*)(ws + off);                      // ROWBLK int
    off += (size_t)ROWBLK * sizeof(int);
    off = (off + 127) & ~(size_t)127;
    float* slotf = (float*)(ws + off);                       // 64 slots x 128 B
    off += (size_t)NSLOT * SLOTSTR * sizeof(float);
    unsigned* subcnt = (unsigned*)(ws + off);                // 64 counters x 128 B
    off += (size_t)NSLOT * SLOTSTR * sizeof(unsigned);
    unsigned* master = (unsigned*)(ws + off);
    off += sizeof(unsigned);

    row_kernel<<<ROWBLK, 256, 0, stream>>>(pred, targets, pred_choice,
                                           p16, part_row, part_match,
                                           slotf, subcnt, master);
    pair_kernel<<<PAIRBLK, 256, 0, stream>>>(p16, part_row, part_match,
                                             slotf, subcnt, master, (float*)d_out);
}